// Round 7
// baseline (355.752 us; speedup 1.0000x reference)
//
#include <hip/hip_runtime.h>

#define BH 64
#define S_ 4096
#define D_ 128
#define SCALE 0.25f  // 1/sqrt(n_heads=16)

typedef __attribute__((ext_vector_type(4))) short short4v;
typedef __attribute__((ext_vector_type(8))) short short8v;
typedef __attribute__((ext_vector_type(4))) float f32x4;

__device__ inline unsigned short f2bf(float x) {
  union { float f; unsigned u; } v; v.f = x;
  unsigned r = v.u + 0x7fff + ((v.u >> 16) & 1);
  return (unsigned short)(r >> 16);
}
__device__ inline short8v cat8(short4v a, short4v b) {
  short8v r;
  r[0] = a[0]; r[1] = a[1]; r[2] = a[2]; r[3] = a[3];
  r[4] = b[0]; r[5] = b[1]; r[6] = b[2]; r[7] = b[3];
  return r;
}
__device__ inline short4v tr16(unsigned addr) {
  short4v r;
  asm volatile("ds_read_b64_tr_b16 %0, %1" : "=v"(r) : "v"(addr));
  return r;
}
__device__ inline void cvt_pair(float x0, float x1, unsigned& hi, unsigned& lo) {
  unsigned u0 = __float_as_uint(x0), u1 = __float_as_uint(x1);
  unsigned m0 = u0 & 0xffff0000u, m1 = u1 & 0xffff0000u;
  hi = m1 | (u0 >> 16);
  float l0 = x0 - __uint_as_float(m0);
  float l1 = x1 - __uint_as_float(m1);
  lo = (__float_as_uint(l1) & 0xffff0000u) | (__float_as_uint(l0) >> 16);
}

#define TILE_B2 8192            // bytes per tile
#define TILE_U2 2048            // uints per tile
#define TILE_SH2 4096           // shorts per tile
#define BUF_B2  (4 * TILE_B2)
#define BUF_SH2 (4 * TILE_SH2)

// MODE: 0 = real kernel (writes part). 1 = NOLOAD probe (no global loads,
// cvt/ds_write on opaque regs, tr+MFMA+sync kept). 2 = NOSTAGE probe
// (tr+MFMA+sync only). Probes write nothing; results kept alive via asm.
template <int NKS, int MODE, bool ATOMIC>
__device__ __forceinline__ void qk_body(const float* __restrict__ q,
                                        const float* __restrict__ k,
                                        float* __restrict__ part, int repeat) {
  constexpr int schunk = S_ / NKS;
  constexpr int nsteps = schunk / 32;
  static_assert(nsteps % 2 == 0, "nsteps must be even");
  const int bh = blockIdx.x;
  const int ks = blockIdx.y;
  const float* qb = q + (size_t)bh * S_ * D_ + (size_t)ks * schunk * D_;
  const float* kb = k + (size_t)bh * S_ * D_ + (size_t)ks * schunk * D_;

  __shared__ alignas(16) short lds[2 * BUF_SH2];
  unsigned* ldsU0 = (unsigned*)&lds[0];
  unsigned* ldsU1 = (unsigned*)&lds[BUF_SH2];
  const unsigned base_u = (unsigned)(uintptr_t)&lds[0];

  const int tid = threadIdx.x;
  const int wv = tid >> 6, lane = tid & 63;
  const int wm = wv & 3;
  const int wn = wv >> 2;

  f32x4 acc[2][4];
#pragma unroll
  for (int a = 0; a < 2; ++a)
#pragma unroll
    for (int b = 0; b < 4; ++b) acc[a][b] = (f32x4){0.f, 0.f, 0.f, 0.f};

  const unsigned lconst = ((unsigned)(lane >> 4) << 10) |
                          ((unsigned)((lane & 15) >> 2) << 5) |
                          ((unsigned)(lane & 3) << 3);
  const unsigned trbase = base_u + lconst;
  const unsigned aQ0 = trbase;
  const unsigned aK0 = trbase + 2u * TILE_B2;
  const unsigned aQ1 = aQ0 + BUF_B2;
  const unsigned aK1 = aK0 + BUF_B2;

  const int row0 = ((tid >> 7) << 2) | ((tid >> 2) & 3);
  const int col0 = (((tid >> 4) & 7) << 4) | ((tid & 3) << 2);

  float4 qr[2], kr[2];
  if (MODE != 0) {
    qr[0] = make_float4(0.5f, 1.5f, 2.5f, 3.5f);
    qr[1] = qr[0]; kr[0] = qr[0]; kr[1] = qr[0];
    asm volatile("" : "+v"(qr[0].x), "+v"(qr[0].y), "+v"(qr[0].z), "+v"(qr[0].w),
                      "+v"(qr[1].x), "+v"(qr[1].y), "+v"(qr[1].z), "+v"(qr[1].w),
                      "+v"(kr[0].x), "+v"(kr[0].y), "+v"(kr[0].z), "+v"(kr[0].w),
                      "+v"(kr[1].x), "+v"(kr[1].y), "+v"(kr[1].z), "+v"(kr[1].w));
  }

  auto load_step = [&](int st) {
    size_t o0 = (size_t)(st * 32 + row0) * D_ + col0;
    size_t o1 = o0 + (size_t)16 * D_;
    qr[0] = *(const float4*)(qb + o0);
    qr[1] = *(const float4*)(qb + o1);
    kr[0] = *(const float4*)(kb + o0);
    kr[1] = *(const float4*)(kb + o1);
  };
  auto cvt_store = [&](unsigned* bufU) {
#pragma unroll
    for (int i = 0; i < 2; ++i) {
      unsigned off = (unsigned)(tid + i * 512) * 2;
      unsigned h0, l0, h1, l1;
      cvt_pair(qr[i].x, qr[i].y, h0, l0);
      cvt_pair(qr[i].z, qr[i].w, h1, l1);
      *(uint2*)(bufU + off) = make_uint2(h0, h1);
      *(uint2*)(bufU + TILE_U2 + off) = make_uint2(l0, l1);
      cvt_pair(kr[i].x, kr[i].y, h0, l0);
      cvt_pair(kr[i].z, kr[i].w, h1, l1);
      *(uint2*)(bufU + 2 * TILE_U2 + off) = make_uint2(h0, h1);
      *(uint2*)(bufU + 3 * TILE_U2 + off) = make_uint2(l0, l1);
    }
  };

  auto iter = [&](int st, unsigned aQb, unsigned aKb, unsigned* stageU) {
    short4v Bf[4][2][2];
#pragma unroll
    for (int b = 0; b < 4; ++b) {
      unsigned cb = (unsigned)(wn * 4 + b) << 7;
#pragma unroll
      for (int ver = 0; ver < 2; ++ver)
#pragma unroll
        for (int kh = 0; kh < 2; ++kh)
          Bf[b][ver][kh] = tr16(aKb + ver * TILE_B2 + kh * 4096 + cb);
    }
    short4v Af[2][2][2];
#pragma unroll
    for (int a = 0; a < 2; ++a) {
      unsigned cb = (unsigned)(wm * 2 + a) << 7;
#pragma unroll
      for (int ver = 0; ver < 2; ++ver)
#pragma unroll
        for (int kh = 0; kh < 2; ++kh)
          Af[a][ver][kh] = tr16(aQb + ver * TILE_B2 + kh * 4096 + cb);
    }
    if (MODE != 2) {
      if (st + 1 < nsteps) cvt_store(stageU);
    }
    if (MODE == 0) {
      if (st + 2 < nsteps) load_step(st + 2);
    }
    asm volatile("s_waitcnt lgkmcnt(0)" ::: "memory");
    __builtin_amdgcn_sched_barrier(0);
#pragma unroll
    for (int a = 0; a < 2; ++a) {
      short8v ah = cat8(Af[a][0][0], Af[a][0][1]);
      short8v al = cat8(Af[a][1][0], Af[a][1][1]);
#pragma unroll
      for (int b = 0; b < 4; ++b) {
        short8v bh_ = cat8(Bf[b][0][0], Bf[b][0][1]);
        short8v bl_ = cat8(Bf[b][1][0], Bf[b][1][1]);
        acc[a][b] = __builtin_amdgcn_mfma_f32_16x16x32_bf16(ah, bh_, acc[a][b], 0, 0, 0);
        acc[a][b] = __builtin_amdgcn_mfma_f32_16x16x32_bf16(ah, bl_, acc[a][b], 0, 0, 0);
        acc[a][b] = __builtin_amdgcn_mfma_f32_16x16x32_bf16(al, bh_, acc[a][b], 0, 0, 0);
      }
    }
    __builtin_amdgcn_s_barrier();
  };

  for (int rep = 0; rep < repeat; ++rep) {
    if (MODE == 0) {
      load_step(0);
      cvt_store(ldsU0);
      if (nsteps > 1) load_step(1);
      asm volatile("s_waitcnt lgkmcnt(0)" ::: "memory");
    } else if (MODE == 1) {
      cvt_store(ldsU0);
      asm volatile("s_waitcnt lgkmcnt(0)" ::: "memory");
    }
    __builtin_amdgcn_s_barrier();
    for (int st = 0; st < nsteps; st += 2) {
      iter(st, aQ0, aK0, ldsU1);
      iter(st + 1, aQ1, aK1, ldsU0);
    }
  }

  if (MODE == 0) {
    if (!ATOMIC) {
      float* dst = part + ((size_t)ks * BH + bh) * D_ * D_;
#pragma unroll
      for (int a = 0; a < 2; ++a)
#pragma unroll
        for (int b = 0; b < 4; ++b) {
          int e = (wn * 4 + b) * 16 + (lane & 15);
#pragma unroll
          for (int r = 0; r < 4; ++r) {
            int d = (wm * 2 + a) * 16 + ((lane >> 4) << 2) + r;
            dst[(size_t)d * D_ + e] = acc[a][b][r] * SCALE;
          }
        }
    } else {
      float* dst = part + (size_t)bh * D_ * D_;
#pragma unroll
      for (int a = 0; a < 2; ++a)
#pragma unroll
        for (int b = 0; b < 4; ++b) {
          int e = (wn * 4 + b) * 16 + (lane & 15);
#pragma unroll
          for (int r = 0; r < 4; ++r) {
            int d = (wm * 2 + a) * 16 + ((lane >> 4) << 2) + r;
            atomicAdd(&dst[(size_t)d * D_ + e], acc[a][b][r] * SCALE);
          }
        }
    }
  } else {
    // keep all results alive without any memory traffic (rule #17)
#pragma unroll
    for (int a = 0; a < 2; ++a)
#pragma unroll
      for (int b = 0; b < 4; ++b)
#pragma unroll
        for (int r = 0; r < 4; ++r)
          asm volatile("" :: "v"(acc[a][b][r]));
  }
}

template <int NKS, bool ATOMIC>
__global__ __launch_bounds__(512, 2) void qk_mfma(const float* __restrict__ q,
                                                  const float* __restrict__ k,
                                                  float* __restrict__ part) {
  qk_body<NKS, 0, ATOMIC>(q, k, part, 1);
}

// Diagnostic probes (outputs unused; distinct names so rocprof rows identify them)
__global__ __launch_bounds__(512, 2) void qk_noload(const float* __restrict__ q,
                                                    const float* __restrict__ k) {
  qk_body<8, 1, false>(q, k, nullptr, 4);
}
__global__ __launch_bounds__(512, 2) void qk_nostage(const float* __restrict__ q,
                                                     const float* __restrict__ k) {
  qk_body<8, 2, false>(q, k, nullptr, 8);
}

// ---------------------------------------------------------------------------
template <int NKS>
__global__ __launch_bounds__(256) void softmax_k(const float* __restrict__ part,
                                                 short* __restrict__ Pg) {
  const int bh = blockIdx.x;
  const int wv = threadIdx.x >> 6, lane = threadIdx.x & 63;
  const size_t kstride = (size_t)BH * D_ * D_;
  const float* base = part + (size_t)bh * D_ * D_;
  short* dst = Pg + (size_t)bh * D_ * D_;
#pragma unroll
  for (int i = 0; i < 8; ++i) {
    int d = blockIdx.y * 32 + wv * 8 + i;
    float v0 = 0.f, v1 = 0.f;
    for (int ks2 = 0; ks2 < NKS; ++ks2) {
      const float* row = base + ks2 * kstride + (size_t)d * D_;
      v0 += row[lane];
      v1 += row[lane + 64];
    }
    float m = fmaxf(v0, v1);
#pragma unroll
    for (int off = 32; off; off >>= 1) m = fmaxf(m, __shfl_xor(m, off, 64));
    float e0 = __expf(v0 - m), e1 = __expf(v1 - m);
    float s = e0 + e1;
#pragma unroll
    for (int off = 32; off; off >>= 1) s += __shfl_xor(s, off, 64);
    float inv = 1.f / s;
    dst[(size_t)d * D_ + lane] = (short)f2bf(e0 * inv);
    dst[(size_t)d * D_ + lane + 64] = (short)f2bf(e1 * inv);
  }
}

// ---------------------------------------------------------------------------
__global__ __launch_bounds__(256) void pv_mfma(const short* __restrict__ Pg,
                                               const float* __restrict__ v,
                                               float* __restrict__ out) {
  const int bh = blockIdx.x;
  const int s0 = blockIdx.y * 128;
  const float* vb = v + (size_t)bh * S_ * D_;
  __shared__ alignas(16) short P_lds[128 * 136];
  __shared__ alignas(16) short V_lds[128 * 36];
  const int tid = threadIdx.x;
  const int wv = tid >> 6, lane = tid & 63;

  const short* Pb = Pg + (size_t)bh * D_ * D_;
#pragma unroll
  for (int i = 0; i < 8; ++i) {
    int idx8 = tid + i * 256;
    int row = idx8 >> 4, c8 = idx8 & 15;
    short8v val = *(const short8v*)(Pb + row * 128 + c8 * 8);
    *(short8v*)(P_lds + row * 136 + c8 * 8) = val;
  }

  f32x4 acc[8][2];
#pragma unroll
  for (int i = 0; i < 8; ++i)
#pragma unroll
    for (int j = 0; j < 2; ++j) acc[i][j] = (f32x4){0.f, 0.f, 0.f, 0.f};

#pragma unroll
  for (int es = 0; es < 4; ++es) {
    __syncthreads();
#pragma unroll
    for (int i = 0; i < 4; ++i) {
      int idx4 = tid + i * 256;
      int s = idx4 >> 3, c4 = idx4 & 7;
      float4 x = *(const float4*)(vb + (size_t)(s0 + s) * D_ + es * 32 + c4 * 4);
      short4v h;
      h[0] = (short)f2bf(x.x); h[1] = (short)f2bf(x.y);
      h[2] = (short)f2bf(x.z); h[3] = (short)f2bf(x.w);
      *(short4v*)(V_lds + s * 36 + c4 * 4) = h;
    }
    __syncthreads();

    short8v a[8];
#pragma unroll
    for (int mt = 0; mt < 8; ++mt) {
      int d = mt * 16 + (lane & 15);
      const short* pr = P_lds + d * 136 + es * 32 + ((lane >> 4) << 2);
      a[mt] = cat8(*(const short4v*)pr, *(const short4v*)(pr + 16));
    }
#pragma unroll
    for (int nl = 0; nl < 2; ++nl) {
      int srow = (wv * 2 + nl) * 16 + (lane & 15);
      const short* vr = V_lds + srow * 36 + ((lane >> 4) << 2);
      short8v b = cat8(*(const short4v*)vr, *(const short4v*)(vr + 16));
#pragma unroll
      for (int mt = 0; mt < 8; ++mt)
        acc[mt][nl] = __builtin_amdgcn_mfma_f32_16x16x32_bf16(a[mt], b, acc[mt][nl], 0, 0, 0);
    }
  }

  float* ob = out + (size_t)bh * D_ * S_ + s0;
#pragma unroll
  for (int mt = 0; mt < 8; ++mt)
#pragma unroll
    for (int nl = 0; nl < 2; ++nl) {
      int sc = (wv * 2 + nl) * 16 + (lane & 15);
#pragma unroll
      for (int r = 0; r < 4; ++r) {
        int d = mt * 16 + ((lane >> 4) << 2) + r;
        ob[(size_t)d * S_ + sc] = acc[mt][nl][r];
      }
    }
}

extern "C" void kernel_launch(void* const* d_in, const int* in_sizes, int n_in,
                              void* d_out, int out_size, void* d_ws,
                              size_t ws_size, hipStream_t stream) {
  const float* q = (const float*)d_in[0];
  const float* k = (const float*)d_in[1];
  const float* v = (const float*)d_in[2];
  float* out = (float*)d_out;
  char* ws = (char*)d_ws;

  const size_t PART1 = (size_t)BH * D_ * D_ * sizeof(float);  // 4 MiB
  const size_t PSZ = (size_t)BH * D_ * D_ * sizeof(short);    // 2 MiB

  if (ws_size >= 8 * PART1 + PSZ) {
    float* part = (float*)ws;
    short* Pg = (short*)(ws + 8 * PART1);
    qk_mfma<8, false><<<dim3(BH, 8), 512, 0, stream>>>(q, k, part);
    softmax_k<8><<<dim3(BH, 4), 256, 0, stream>>>(part, Pg);
    pv_mfma<<<dim3(BH, 32), 256, 0, stream>>>(Pg, v, out);
  } else {
    float* part = (float*)ws;
    short* Pg = (short*)(ws + PART1);
    hipMemsetAsync(ws, 0, PART1, stream);
    qk_mfma<16, true><<<dim3(BH, 16), 512, 0, stream>>>(q, k, part);
    softmax_k<1><<<dim3(BH, 4), 256, 0, stream>>>(part, Pg);
    pv_mfma<<<dim3(BH, 32), 256, 0, stream>>>(Pg, v, out);
  }

  // ---- diagnostic probes (outputs unused; see round-7 analysis) ----
  qk_noload<<<dim3(BH, 8), 512, 0, stream>>>(q, k);
  qk_nostage<<<dim3(BH, 8), 512, 0, stream>>>(q, k);
}

// Round 8
// 153.418 us; speedup vs baseline: 2.3188x; 2.3188x over previous
//
#include <hip/hip_runtime.h>

#define BH 64
#define S_ 4096
#define D_ 128
#define SCALE 0.25f  // 1/sqrt(n_heads=16)

typedef __attribute__((ext_vector_type(4))) short short4v;
typedef __attribute__((ext_vector_type(8))) short short8v;
typedef __attribute__((ext_vector_type(4))) float f32x4;

__device__ inline unsigned short f2bf(float x) {
  union { float f; unsigned u; } v; v.f = x;
  unsigned r = v.u + 0x7fff + ((v.u >> 16) & 1);
  return (unsigned short)(r >> 16);
}
__device__ inline short8v cat8(short4v a, short4v b) {
  short8v r;
  r[0] = a[0]; r[1] = a[1]; r[2] = a[2]; r[3] = a[3];
  r[4] = b[0]; r[5] = b[1]; r[6] = b[2]; r[7] = b[3];
  return r;
}
// Hardware transpose read (semantics verified rounds 2-7).
__device__ inline short4v tr16(unsigned addr) {
  short4v r;
  asm volatile("ds_read_b64_tr_b16 %0, %1" : "=v"(r) : "v"(addr));
  return r;
}
// Truncation-based hi/lo bf16 split of two floats, packed (elem0 in low 16).
__device__ inline void cvt_pair(float x0, float x1, unsigned& hi, unsigned& lo) {
  unsigned u0 = __float_as_uint(x0), u1 = __float_as_uint(x1);
  unsigned m0 = u0 & 0xffff0000u, m1 = u1 & 0xffff0000u;
  hi = m1 | (u0 >> 16);
  float l0 = x0 - __uint_as_float(m0);
  float l1 = x1 - __uint_as_float(m1);
  lo = (__float_as_uint(l1) & 0xffff0000u) | (__float_as_uint(l0) >> 16);
}
// Async global->LDS DMA, 16 B per lane (dest = uniform base + lane*16).
__device__ __forceinline__ void async_copy16(void* lds_dst, const void* g_src) {
  __builtin_amdgcn_global_load_lds(
      (const __attribute__((address_space(1))) void*)g_src,
      (__attribute__((address_space(3))) void*)lds_dst, 16, 0, 0);
}

// ---------------------------------------------------------------------------
// Phase A: split-K QK^T, split-bf16 (hi/lo) 3-pass MFMA.
// part[ks][bh][d][e] = SCALE * sum_{s in chunk} q[s][d]*k[s][e]
//
// NEW staging: global_load_lds DMAs raw fp32 rows into a single LDS F-buffer
// (row-major [32][128] per matrix); a convert phase reads F (ds_read_b128),
// does the hi/lo split, writes the bf16 4x16-subtile tiles (R6-verified
// layout + tr16 mapping). Per-step pipeline (single F buffer, bf16 single):
//   invariant: bf16 = chunk st, F = chunk st+1 (DMA completed)
//   A: 24 tr16 (st) + 4 ds_read_b128 (F -> regs, st+1); lgkm(0); barrier
//   C: issue 4 DMA (st+2) -> F          (F was freed by the barrier)
//   D: convert regs -> bf16 tiles (st+1)
//   E: 24 MFMA (st)
//   end: vmcnt(0) lgkm(0); barrier      (DMA landed, bf16 ready)
// LDS = 32 KB bf16 + 32 KB F = 64 KB -> 2 blocks/CU.
// ---------------------------------------------------------------------------
#define TILE_B2 8192            // bytes per bf16 tile
#define TILE_U2 2048            // uints per bf16 tile
#define TILE_SH2 4096           // shorts per bf16 tile
#define F_SH 16384              // short index of F region (byte 32768)
#define F_ROW_F 128             // floats per F row

template <int NKS, bool ATOMIC>
__global__ __launch_bounds__(512, 2) void qk_mfma(const float* __restrict__ q,
                                                  const float* __restrict__ k,
                                                  float* __restrict__ part) {
  constexpr int schunk = S_ / NKS;
  constexpr int nsteps = schunk / 32;
  const int bh = blockIdx.x;
  const int ks = blockIdx.y;
  const float* qb = q + (size_t)bh * S_ * D_ + (size_t)ks * schunk * D_;
  const float* kb = k + (size_t)bh * S_ * D_ + (size_t)ks * schunk * D_;

  __shared__ alignas(16) short lds[F_SH + 2 * 8192];  // 32KB bf16 + 32KB F
  unsigned* bufU = (unsigned*)&lds[0];
  const unsigned base_u = (unsigned)(uintptr_t)&lds[0];
  float* FQ = (float*)&lds[F_SH];            // [32][128] fp32
  float* FK = (float*)&lds[F_SH + 8192];     // [32][128] fp32

  const int tid = threadIdx.x;
  const int wv = tid >> 6, lane = tid & 63;
  const int wm = wv & 3;   // m-block: 32 d
  const int wn = wv >> 2;  // n-block: 64 e

  f32x4 acc[2][4];
#pragma unroll
  for (int a = 0; a < 2; ++a)
#pragma unroll
    for (int b = 0; b < 4; ++b) acc[a][b] = (f32x4){0.f, 0.f, 0.f, 0.f};

  // tr-read per-lane constant (R6-verified subtile mapping)
  const unsigned lconst = ((unsigned)(lane >> 4) << 10) |
                          ((unsigned)((lane & 15) >> 2) << 5) |
                          ((unsigned)(lane & 3) << 3);
  const unsigned trbase = base_u + lconst;
  const unsigned aQ = trbase;                 // Qhi at 0, Qlo at +TILE_B2
  const unsigned aK = trbase + 2u * TILE_B2;  // Khi, Klo

  // convert-phase geometry: thread t owns bf16 linear slots t and t+512/tile
  const int row0 = ((tid >> 7) << 2) | ((tid >> 2) & 3);
  const int col0 = (((tid >> 4) & 7) << 4) | ((tid & 3) << 2);

  // DMA geometry: wave wv, instr i -> rows (wv&3)*8 + i*2 .. +1 of Q (wv<4)
  // or K (wv>=4); lane l covers row +(l>>5), floats (l&31)*4 .. +3.
  const int mK = wv >> 2;           // 0 = Q, 1 = K
  const int w4 = wv & 3;
  const float* matp = mK ? kb : qb;
  short* ldsF = &lds[F_SH + mK * 8192];

  auto dma_step = [&](int st) {
#pragma unroll
    for (int i = 0; i < 4; ++i) {
      const float* src =
          matp + (size_t)(st * 32 + w4 * 8 + i * 2 + (lane >> 5)) * D_ +
          (lane & 31) * 4;
      async_copy16(ldsF + (size_t)(w4 * 4 + i) * 512, src);
    }
  };

  float4 freg[4];
  auto f_read = [&]() {
    freg[0] = *(const float4*)(FQ + row0 * F_ROW_F + col0);
    freg[1] = *(const float4*)(FQ + (row0 + 16) * F_ROW_F + col0);
    freg[2] = *(const float4*)(FK + row0 * F_ROW_F + col0);
    freg[3] = *(const float4*)(FK + (row0 + 16) * F_ROW_F + col0);
  };
  auto cvt_store = [&]() {
#pragma unroll
    for (int i = 0; i < 2; ++i) {
      unsigned off = (unsigned)(tid + i * 512) * 2;  // uint index of 8B slot
      unsigned h0, l0, h1, l1;
      cvt_pair(freg[i].x, freg[i].y, h0, l0);
      cvt_pair(freg[i].z, freg[i].w, h1, l1);
      *(uint2*)(bufU + off) = make_uint2(h0, h1);
      *(uint2*)(bufU + TILE_U2 + off) = make_uint2(l0, l1);
      cvt_pair(freg[i + 2].x, freg[i + 2].y, h0, l0);
      cvt_pair(freg[i + 2].z, freg[i + 2].w, h1, l1);
      *(uint2*)(bufU + 2 * TILE_U2 + off) = make_uint2(h0, h1);
      *(uint2*)(bufU + 3 * TILE_U2 + off) = make_uint2(l0, l1);
    }
  };

  // ---- prologue: F <- chunk0; convert chunk0 -> bf16; F <- chunk1 ----
  dma_step(0);
  asm volatile("s_waitcnt vmcnt(0)" ::: "memory");
  __builtin_amdgcn_s_barrier();
  f_read();
  asm volatile("s_waitcnt lgkmcnt(0)" ::: "memory");
  __builtin_amdgcn_sched_barrier(0);
  __builtin_amdgcn_s_barrier();            // F free
  if (nsteps > 1) dma_step(1);
  cvt_store();                             // bf16 <- chunk 0
  asm volatile("s_waitcnt vmcnt(0) lgkmcnt(0)" ::: "memory");
  __builtin_amdgcn_sched_barrier(0);
  __builtin_amdgcn_s_barrier();

  for (int st = 0; st < nsteps; ++st) {
    // ---- A: tr reads (st) + F reads (st+1), one drain, barrier ----
    short4v Bf[4][2][2];
#pragma unroll
    for (int b = 0; b < 4; ++b) {
      unsigned cb = (unsigned)(wn * 4 + b) << 7;
#pragma unroll
      for (int ver = 0; ver < 2; ++ver)
#pragma unroll
        for (int kh = 0; kh < 2; ++kh)
          Bf[b][ver][kh] = tr16(aK + ver * TILE_B2 + kh * 4096 + cb);
    }
    short4v Af[2][2][2];
#pragma unroll
    for (int a = 0; a < 2; ++a) {
      unsigned cb = (unsigned)(wm * 2 + a) << 7;
#pragma unroll
      for (int ver = 0; ver < 2; ++ver)
#pragma unroll
        for (int kh = 0; kh < 2; ++kh)
          Af[a][ver][kh] = tr16(aQ + ver * TILE_B2 + kh * 4096 + cb);
    }
    if (st + 1 < nsteps) f_read();
    asm volatile("s_waitcnt lgkmcnt(0)" ::: "memory");
    __builtin_amdgcn_sched_barrier(0);
    __builtin_amdgcn_s_barrier();          // bf16 + F consumed

    // ---- C: DMA chunk st+2 into F (async, drains at end-of-step) ----
    if (st + 2 < nsteps) dma_step(st + 2);
    // ---- D: convert chunk st+1 -> bf16 tiles ----
    if (st + 1 < nsteps) cvt_store();

    // ---- E: MFMA (st) ----
#pragma unroll
    for (int a = 0; a < 2; ++a) {
      short8v ah = cat8(Af[a][0][0], Af[a][0][1]);
      short8v al = cat8(Af[a][1][0], Af[a][1][1]);
#pragma unroll
      for (int b = 0; b < 4; ++b) {
        short8v bh_ = cat8(Bf[b][0][0], Bf[b][0][1]);
        short8v bl_ = cat8(Bf[b][1][0], Bf[b][1][1]);
        acc[a][b] = __builtin_amdgcn_mfma_f32_16x16x32_bf16(ah, bh_, acc[a][b], 0, 0, 0);
        acc[a][b] = __builtin_amdgcn_mfma_f32_16x16x32_bf16(ah, bl_, acc[a][b], 0, 0, 0);
        acc[a][b] = __builtin_amdgcn_mfma_f32_16x16x32_bf16(al, bh_, acc[a][b], 0, 0, 0);
      }
    }
    asm volatile("s_waitcnt vmcnt(0) lgkmcnt(0)" ::: "memory");
    __builtin_amdgcn_sched_barrier(0);
    __builtin_amdgcn_s_barrier();          // DMA landed, bf16 ready
  }

  // epilogue: D layout col=lane&15, row=(lane>>4)*4+reg
  if (!ATOMIC) {
    float* dst = part + ((size_t)ks * BH + bh) * D_ * D_;
#pragma unroll
    for (int a = 0; a < 2; ++a)
#pragma unroll
      for (int b = 0; b < 4; ++b) {
        int e = (wn * 4 + b) * 16 + (lane & 15);
#pragma unroll
        for (int r = 0; r < 4; ++r) {
          int d = (wm * 2 + a) * 16 + ((lane >> 4) << 2) + r;
          dst[(size_t)d * D_ + e] = acc[a][b][r] * SCALE;
        }
      }
  } else {
    float* dst = part + (size_t)bh * D_ * D_;
#pragma unroll
    for (int a = 0; a < 2; ++a)
#pragma unroll
      for (int b = 0; b < 4; ++b) {
        int e = (wn * 4 + b) * 16 + (lane & 15);
#pragma unroll
        for (int r = 0; r < 4; ++r) {
          int d = (wm * 2 + a) * 16 + ((lane >> 4) << 2) + r;
          atomicAdd(&dst[(size_t)d * D_ + e], acc[a][b][r] * SCALE);
        }
      }
  }
}

// ---------------------------------------------------------------------------
// Phase B: combine partials + row softmax -> P as bf16 (linear [d][e])
// ---------------------------------------------------------------------------
template <int NKS>
__global__ __launch_bounds__(256) void softmax_k(const float* __restrict__ part,
                                                 short* __restrict__ Pg) {
  const int bh = blockIdx.x;
  const int wv = threadIdx.x >> 6, lane = threadIdx.x & 63;
  const size_t kstride = (size_t)BH * D_ * D_;
  const float* base = part + (size_t)bh * D_ * D_;
  short* dst = Pg + (size_t)bh * D_ * D_;
#pragma unroll
  for (int i = 0; i < 8; ++i) {
    int d = blockIdx.y * 32 + wv * 8 + i;
    float v0 = 0.f, v1 = 0.f;
    for (int ks2 = 0; ks2 < NKS; ++ks2) {
      const float* row = base + ks2 * kstride + (size_t)d * D_;
      v0 += row[lane];
      v1 += row[lane + 64];
    }
    float m = fmaxf(v0, v1);
#pragma unroll
    for (int off = 32; off; off >>= 1) m = fmaxf(m, __shfl_xor(m, off, 64));
    float e0 = __expf(v0 - m), e1 = __expf(v1 - m);
    float s = e0 + e1;
#pragma unroll
    for (int off = 32; off; off >>= 1) s += __shfl_xor(s, off, 64);
    float inv = 1.f / s;
    dst[(size_t)d * D_ + lane] = (short)f2bf(e0 * inv);
    dst[(size_t)d * D_ + lane + 64] = (short)f2bf(e1 * inv);
  }
}

// ---------------------------------------------------------------------------
// Phase C: out[d][s] = sum_e P[d][e] * v[s][e] — bf16 MFMA over contiguous e.
// ---------------------------------------------------------------------------
__global__ __launch_bounds__(256) void pv_mfma(const short* __restrict__ Pg,
                                               const float* __restrict__ v,
                                               float* __restrict__ out) {
  const int bh = blockIdx.x;
  const int s0 = blockIdx.y * 128;
  const float* vb = v + (size_t)bh * S_ * D_;
  __shared__ alignas(16) short P_lds[128 * 136];
  __shared__ alignas(16) short V_lds[128 * 36];
  const int tid = threadIdx.x;
  const int wv = tid >> 6, lane = tid & 63;

  const short* Pb = Pg + (size_t)bh * D_ * D_;
#pragma unroll
  for (int i = 0; i < 8; ++i) {
    int idx8 = tid + i * 256;
    int row = idx8 >> 4, c8 = idx8 & 15;
    short8v val = *(const short8v*)(Pb + row * 128 + c8 * 8);
    *(short8v*)(P_lds + row * 136 + c8 * 8) = val;
  }

  f32x4 acc[8][2];
#pragma unroll
  for (int i = 0; i < 8; ++i)
#pragma unroll
    for (int j = 0; j < 2; ++j) acc[i][j] = (f32x4){0.f, 0.f, 0.f, 0.f};

#pragma unroll
  for (int es = 0; es < 4; ++es) {
    __syncthreads();
#pragma unroll
    for (int i = 0; i < 4; ++i) {
      int idx4 = tid + i * 256;
      int s = idx4 >> 3, c4 = idx4 & 7;
      float4 x = *(const float4*)(vb + (size_t)(s0 + s) * D_ + es * 32 + c4 * 4);
      short4v h;
      h[0] = (short)f2bf(x.x); h[1] = (short)f2bf(x.y);
      h[2] = (short)f2bf(x.z); h[3] = (short)f2bf(x.w);
      *(short4v*)(V_lds + s * 36 + c4 * 4) = h;
    }
    __syncthreads();

    short8v a[8];
#pragma unroll
    for (int mt = 0; mt < 8; ++mt) {
      int d = mt * 16 + (lane & 15);
      const short* pr = P_lds + d * 136 + es * 32 + ((lane >> 4) << 2);
      a[mt] = cat8(*(const short4v*)pr, *(const short4v*)(pr + 16));
    }
#pragma unroll
    for (int nl = 0; nl < 2; ++nl) {
      int srow = (wv * 2 + nl) * 16 + (lane & 15);
      const short* vr = V_lds + srow * 36 + ((lane >> 4) << 2);
      short8v b = cat8(*(const short4v*)vr, *(const short4v*)(vr + 16));
#pragma unroll
      for (int mt = 0; mt < 8; ++mt)
        acc[mt][nl] = __builtin_amdgcn_mfma_f32_16x16x32_bf16(a[mt], b, acc[mt][nl], 0, 0, 0);
    }
  }

  float* ob = out + (size_t)bh * D_ * S_ + s0;
#pragma unroll
  for (int mt = 0; mt < 8; ++mt)
#pragma unroll
    for (int nl = 0; nl < 2; ++nl) {
      int sc = (wv * 2 + nl) * 16 + (lane & 15);
#pragma unroll
      for (int r = 0; r < 4; ++r) {
        int d = mt * 16 + ((lane >> 4) << 2) + r;
        ob[(size_t)d * S_ + sc] = acc[mt][nl][r];
      }
    }
}

extern "C" void kernel_launch(void* const* d_in, const int* in_sizes, int n_in,
                              void* d_out, int out_size, void* d_ws,
                              size_t ws_size, hipStream_t stream) {
  const float* q = (const float*)d_in[0];
  const float* k = (const float*)d_in[1];
  const float* v = (const float*)d_in[2];
  float* out = (float*)d_out;
  char* ws = (char*)d_ws;

  const size_t PART1 = (size_t)BH * D_ * D_ * sizeof(float);  // 4 MiB
  const size_t PSZ = (size_t)BH * D_ * D_ * sizeof(short);    // 2 MiB

  if (ws_size >= 8 * PART1 + PSZ) {
    float* part = (float*)ws;
    short* Pg = (short*)(ws + 8 * PART1);
    qk_mfma<8, false><<<dim3(BH, 8), 512, 0, stream>>>(q, k, part);
    softmax_k<8><<<dim3(BH, 4), 256, 0, stream>>>(part, Pg);
    pv_mfma<<<dim3(BH, 32), 256, 0, stream>>>(Pg, v, out);
  } else {
    float* part = (float*)ws;
    short* Pg = (short*)(ws + PART1);
    hipMemsetAsync(ws, 0, PART1, stream);
    qk_mfma<16, true><<<dim3(BH, 16), 512, 0, stream>>>(q, k, part);
    softmax_k<1><<<dim3(BH, 4), 256, 0, stream>>>(part, Pg);
    pv_mfma<<<dim3(BH, 32), 256, 0, stream>>>(Pg, v, out);
  }
}